// Round 1
// baseline (603.302 us; speedup 1.0000x reference)
//
#include <hip/hip_runtime.h>
#include <hip/hip_bf16.h>

typedef __attribute__((ext_vector_type(8))) short short8_t;
typedef __attribute__((ext_vector_type(4))) float f32x4;

__device__ __forceinline__ short f2bf(float x){
  union { float f; unsigned u; } v; v.f = x;
  unsigned r = v.u + 0x7fffu + ((v.u >> 16) & 1u);
  return (short)(r >> 16);
}

__global__ __launch_bounds__(256) void k_zero_i32(int* __restrict__ p, int n){
  int i = blockIdx.x*256 + threadIdx.x;
  if (i < n) p[i] = 0;
}

__global__ __launch_bounds__(256) void k_hist(const int* __restrict__ ei, int* __restrict__ cnt, int E){
  int i = blockIdx.x*256 + threadIdx.x;
  if (i < E) atomicAdd(&cnt[ei[E + i]], 1);
}

// single-block exclusive scan over cnt -> off (and cursor copy, dinv)
__global__ __launch_bounds__(1024) void k_scan(const int* __restrict__ cnt, int* __restrict__ off,
                                               int* __restrict__ cursor, float* __restrict__ dinv, int N){
  __shared__ int part[1024];
  int t = threadIdx.x;
  int chunk = (N + 1023) >> 10;
  int lo = t*chunk; if (lo > N) lo = N;
  int hi = lo + chunk; if (hi > N) hi = N;
  int s = 0;
  for (int i = lo; i < hi; ++i) s += cnt[i];
  part[t] = s; __syncthreads();
  for (int d = 1; d < 1024; d <<= 1){
    int v = (t >= d) ? part[t-d] : 0;
    __syncthreads();
    part[t] += v;
    __syncthreads();
  }
  int run = (t == 0) ? 0 : part[t-1];
  for (int i = lo; i < hi; ++i){
    off[i] = run; cursor[i] = run;
    dinv[i] = rsqrtf((float)(cnt[i] + 1));
    run += cnt[i];
  }
  if (t == 1023) off[N] = part[1023];
}

__global__ __launch_bounds__(256) void k_scatter(const int* __restrict__ ei, int* __restrict__ cursor,
                                                 int* __restrict__ ebuf, int E){
  int i = blockIdx.x*256 + threadIdx.x;
  if (i < E){
    int s = ei[i], d = ei[E + i];
    int p = atomicAdd(&cursor[d], 1);
    ebuf[p] = s;
  }
}

// Convert W [K x 64] fp32 -> bf16 fragment layout.
// tid = ((kt*4 + nt)*64 + lane)*8 + e ; element = W[(kt*32 + (lane>>4)*8 + e)*64 + nt*16 + (lane&15)]
__global__ __launch_bounds__(256) void k_wconv(const float* __restrict__ W, short* __restrict__ Wb, int total){
  int tid = blockIdx.x*256 + threadIdx.x;
  if (tid >= total) return;
  int e  = tid & 7;
  int l  = (tid >> 3) & 63;
  int nt = (tid >> 9) & 3;
  int kt = tid >> 11;
  int k  = kt*32 + (l >> 4)*8 + e;
  int col = nt*16 + (l & 15);
  Wb[tid] = f2bf(W[(size_t)k*64 + col]);
}

// C = A[M x K] * W[K x 64]   (K = KTILES*32), A fp32 row-major (lda), W pre-laid-out bf16 fragments.
// One wave per 16-row tile; 4 n-tiles of 16 cols each.
template<int KTILES>
__global__ __launch_bounds__(256) void k_gemm(const float* __restrict__ A, const short* __restrict__ Wb,
                                              float* __restrict__ out, int M, int lda){
  int wid = threadIdx.x >> 6, lane = threadIdx.x & 63;
  int row0 = (blockIdx.x*4 + wid)*16;
  if (row0 >= M) return;
  int r = lane & 15, g = lane >> 4;
  const float* arow = A + (size_t)(row0 + r)*lda + g*8;
  const short8_t* wb = (const short8_t*)Wb + lane;
  f32x4 acc0 = {0.f,0.f,0.f,0.f}, acc1 = acc0, acc2 = acc0, acc3 = acc0;
  #pragma unroll 2
  for (int kt = 0; kt < KTILES; ++kt){
    const float* ap = arow + kt*32;
    float4 a0 = *(const float4*)ap;
    float4 a1 = *(const float4*)(ap + 4);
    short8_t af;
    af[0]=f2bf(a0.x); af[1]=f2bf(a0.y); af[2]=f2bf(a0.z); af[3]=f2bf(a0.w);
    af[4]=f2bf(a1.x); af[5]=f2bf(a1.y); af[6]=f2bf(a1.z); af[7]=f2bf(a1.w);
    short8_t b0 = wb[(kt*4+0)*64];
    short8_t b1 = wb[(kt*4+1)*64];
    short8_t b2 = wb[(kt*4+2)*64];
    short8_t b3 = wb[(kt*4+3)*64];
    acc0 = __builtin_amdgcn_mfma_f32_16x16x32_bf16(af, b0, acc0, 0,0,0);
    acc1 = __builtin_amdgcn_mfma_f32_16x16x32_bf16(af, b1, acc1, 0,0,0);
    acc2 = __builtin_amdgcn_mfma_f32_16x16x32_bf16(af, b2, acc2, 0,0,0);
    acc3 = __builtin_amdgcn_mfma_f32_16x16x32_bf16(af, b3, acc3, 0,0,0);
  }
  // C/D: col = lane&15, row = (lane>>4)*4 + reg  [verified layout]
  float* op = out + (size_t)(row0 + g*4)*64 + r;
  #pragma unroll
  for (int reg = 0; reg < 4; ++reg){
    op[reg*64 +  0] = acc0[reg];
    op[reg*64 + 16] = acc1[reg];
    op[reg*64 + 32] = acc2[reg];
    op[reg*64 + 48] = acc3[reg];
  }
}

// Gather-aggregate: out[i] = relu( dinv[i]^2*h[i] + sum_edges dinv[i]*dinv[s]*h[s] + bias ).
// One wave per node (lane = feature). FUSE: accumulate mean partials per block instead of storing.
template<bool FUSE>
__global__ __launch_bounds__(256) void k_agg(const float* __restrict__ hin, const int* __restrict__ off,
                                             const int* __restrict__ ebuf, const float* __restrict__ dinv,
                                             const float* __restrict__ bias, float* __restrict__ outp, int N){
  int lane = threadIdx.x & 63, wid = threadIdx.x >> 6;
  float b = bias[lane];
  float fsum = 0.f;
  int stride = gridDim.x*4;
  for (int i = blockIdx.x*4 + wid; i < N; i += stride){
    float di = dinv[i];
    float acc = di*di*hin[(size_t)i*64 + lane];
    int j  = off[i];
    int j1 = off[i+1];
    for (; j + 4 <= j1; j += 4){
      int s0 = ebuf[j], s1 = ebuf[j+1], s2 = ebuf[j+2], s3 = ebuf[j+3];
      float w0 = di*dinv[s0], w1 = di*dinv[s1], w2 = di*dinv[s2], w3 = di*dinv[s3];
      acc += w0*hin[(size_t)s0*64 + lane];
      acc += w1*hin[(size_t)s1*64 + lane];
      acc += w2*hin[(size_t)s2*64 + lane];
      acc += w3*hin[(size_t)s3*64 + lane];
    }
    for (; j < j1; ++j){
      int s = ebuf[j];
      acc += di*dinv[s]*hin[(size_t)s*64 + lane];
    }
    float z = fmaxf(acc + b, 0.f);
    if (FUSE) fsum += z;
    else outp[(size_t)i*64 + lane] = z;
  }
  if (FUSE){
    __shared__ float sm[4][64];
    sm[wid][lane] = fsum;
    __syncthreads();
    if (wid == 0)
      outp[(size_t)blockIdx.x*64 + lane] = sm[0][lane] + sm[1][lane] + sm[2][lane] + sm[3][lane];
  }
}

__global__ __launch_bounds__(256) void k_final(const float* __restrict__ part, float* __restrict__ out,
                                               int NB, float invN){
  int f = blockIdx.x;
  float s = 0.f;
  for (int b = threadIdx.x; b < NB; b += 256) s += part[(size_t)b*64 + f];
  __shared__ float sm[256];
  sm[threadIdx.x] = s; __syncthreads();
  for (int d = 128; d > 0; d >>= 1){
    if (threadIdx.x < d) sm[threadIdx.x] += sm[threadIdx.x + d];
    __syncthreads();
  }
  if (threadIdx.x == 0) out[f] = sm[0]*invN;
}

extern "C" void kernel_launch(void* const* d_in, const int* in_sizes, int n_in,
                              void* d_out, int out_size, void* d_ws, size_t ws_size,
                              hipStream_t stream){
  const float* x  = (const float*)d_in[0];
  const int*   ei = (const int*)d_in[1];
  const float* W1 = (const float*)d_in[2];
  const float* b1 = (const float*)d_in[3];
  const float* W2 = (const float*)d_in[4];
  const float* b2 = (const float*)d_in[5];
  float* out = (float*)d_out;

  const int IN = 2048;
  int N = in_sizes[0] / IN;      // 50000
  int E = in_sizes[1] / 2;       // 1.6M

  char* w = (char*)d_ws;
  auto alloc = [&](size_t bytes){ char* p = w; w += (bytes + 255) & ~255ULL; return (void*)p; };
  int*   cnt    = (int*)  alloc((size_t)N*4);
  int*   off    = (int*)  alloc((size_t)(N+1)*4);
  int*   cursor = (int*)  alloc((size_t)N*4);
  float* dinv   = (float*)alloc((size_t)N*4);
  int*   ebuf   = (int*)  alloc((size_t)E*4);
  short* Wb1    = (short*)alloc((size_t)64*2048*2);  // KTILES=64 fragments
  short* Wb2    = (short*)alloc((size_t)2*2048*2);   // KTILES=2 fragments
  float* h1     = (float*)alloc((size_t)N*64*4);     // reused as h2
  float* z1     = (float*)alloc((size_t)N*64*4);
  const int NB2 = 2048;
  float* part   = (float*)alloc((size_t)NB2*64*4);

  int eb = (E + 255)/256;
  k_zero_i32<<<(N+255)/256, 256, 0, stream>>>(cnt, N);
  k_hist   <<<eb, 256, 0, stream>>>(ei, cnt, E);
  k_scan   <<<1, 1024, 0, stream>>>(cnt, off, cursor, dinv, N);
  k_scatter<<<eb, 256, 0, stream>>>(ei, cursor, ebuf, E);
  k_wconv  <<<(64*2048 + 255)/256, 256, 0, stream>>>(W1, Wb1, 64*2048);
  k_wconv  <<<(2*2048  + 255)/256, 256, 0, stream>>>(W2, Wb2, 2*2048);

  int mtiles  = (N + 15)/16;         // 3125
  int gblocks = (mtiles + 3)/4;      // 782
  k_gemm<64><<<gblocks, 256, 0, stream>>>(x,  Wb1, h1, N, 2048);
  k_agg<false><<<NB2, 256, 0, stream>>>(h1, off, ebuf, dinv, b1, z1, N);
  k_gemm<2> <<<gblocks, 256, 0, stream>>>(z1, Wb2, h1, N, 64);
  k_agg<true> <<<NB2, 256, 0, stream>>>(h1, off, ebuf, dinv, b2, part, N);
  k_final  <<<64, 256, 0, stream>>>(part, out, NB2, 1.0f/(float)N);
}

// Round 2
// 595.282 us; speedup vs baseline: 1.0135x; 1.0135x over previous
//
#include <hip/hip_runtime.h>
#include <hip/hip_bf16.h>

typedef __attribute__((ext_vector_type(8))) short short8_t;
typedef __attribute__((ext_vector_type(4))) float f32x4;

__device__ __forceinline__ short f2bf(float x){
  union { float f; unsigned u; } v; v.f = x;
  unsigned r = v.u + 0x7fffu + ((v.u >> 16) & 1u);
  return (short)(r >> 16);
}
__device__ __forceinline__ float bf2f(unsigned short u){
  union { unsigned u; float f; } v; v.u = ((unsigned)u) << 16; return v.f;
}

__global__ __launch_bounds__(256) void k_zero_i32(int* __restrict__ p, int n){
  int i = blockIdx.x*256 + threadIdx.x;
  if (i < n) p[i] = 0;
}

__global__ __launch_bounds__(256) void k_hist(const int* __restrict__ ei, int* __restrict__ cnt, int E){
  int i = blockIdx.x*256 + threadIdx.x;
  if (i < E) atomicAdd(&cnt[ei[E + i]], 1);
}

// single-block exclusive scan over cnt -> off (+cursor copy, dinv)
__global__ __launch_bounds__(1024) void k_scan(const int* __restrict__ cnt, int* __restrict__ off,
                                               int* __restrict__ cursor, float* __restrict__ dinv, int N){
  __shared__ int part[1024];
  int t = threadIdx.x;
  int chunk = (N + 1023) >> 10;
  int lo = t*chunk; if (lo > N) lo = N;
  int hi = lo + chunk; if (hi > N) hi = N;
  int s = 0;
  for (int i = lo; i < hi; ++i) s += cnt[i];
  part[t] = s; __syncthreads();
  for (int d = 1; d < 1024; d <<= 1){
    int v = (t >= d) ? part[t-d] : 0;
    __syncthreads();
    part[t] += v;
    __syncthreads();
  }
  int run = (t == 0) ? 0 : part[t-1];
  for (int i = lo; i < hi; ++i){
    off[i] = run; cursor[i] = run;
    dinv[i] = rsqrtf((float)(cnt[i] + 1));
    run += cnt[i];
  }
  if (t == 1023) off[N] = part[1023];
}

__global__ __launch_bounds__(256) void k_scatter(const int* __restrict__ ei, int* __restrict__ cursor,
                                                 int* __restrict__ ebuf, int E){
  int i = blockIdx.x*256 + threadIdx.x;
  if (i < E){
    int s = ei[i], d = ei[E + i];
    int p = atomicAdd(&cursor[d], 1);
    ebuf[p] = s;
  }
}

// W [K x 64] fp32 -> bf16 fragment layout.
// tid = ((kt*4 + nt)*64 + lane)*8 + e ; element = W[(kt*32 + (lane>>4)*8 + e)*64 + nt*16 + (lane&15)]
__global__ __launch_bounds__(256) void k_wconv(const float* __restrict__ W, short* __restrict__ Wb, int total){
  int tid = blockIdx.x*256 + threadIdx.x;
  if (tid >= total) return;
  int e  = tid & 7;
  int l  = (tid >> 3) & 63;
  int nt = (tid >> 9) & 3;
  int kt = tid >> 11;
  int k  = kt*32 + (l >> 4)*8 + e;
  int col = nt*16 + (l & 15);
  Wb[tid] = f2bf(W[(size_t)k*64 + col]);
}

// C = A[M x K] * W[K x 64], K = KTILES*32. Output: bf16 h' = dinv[row] * (A.W)[row]
// A fp32 (ABF=false) or bf16-ushort (ABF=true), row-major with leading dim lda.
// One wave per 16-row tile, register double-buffered k-loop.
template<int KTILES, bool ABF>
__global__ __launch_bounds__(256) void k_gemm(const float* __restrict__ Af, const unsigned short* __restrict__ Ah,
                                              const short* __restrict__ Wb, const float* __restrict__ dinv,
                                              unsigned short* __restrict__ out, int M, int lda){
  int wid = threadIdx.x >> 6, lane = threadIdx.x & 63;
  int row0 = (blockIdx.x*4 + wid)*16;
  if (row0 >= M) return;
  int r = lane & 15, g = lane >> 4;
  const short8_t* wb = (const short8_t*)Wb + lane;
  f32x4 acc0 = {0.f,0.f,0.f,0.f}, acc1 = acc0, acc2 = acc0, acc3 = acc0;

  short8_t afc, b0c, b1c, b2c, b3c;
  short8_t afn, b0n, b1n, b2n, b3n;

  #define LOAD_A(kt, dst) do { \
    if constexpr (ABF) { \
      dst = *(const short8_t*)(Ah + (size_t)(row0 + r)*lda + (kt)*32 + g*8); \
    } else { \
      const float* ap = Af + (size_t)(row0 + r)*lda + (kt)*32 + g*8; \
      float4 a0 = *(const float4*)ap; \
      float4 a1 = *(const float4*)(ap + 4); \
      dst[0]=f2bf(a0.x); dst[1]=f2bf(a0.y); dst[2]=f2bf(a0.z); dst[3]=f2bf(a0.w); \
      dst[4]=f2bf(a1.x); dst[5]=f2bf(a1.y); dst[6]=f2bf(a1.z); dst[7]=f2bf(a1.w); \
    } } while(0)

  LOAD_A(0, afc);
  b0c = wb[0]; b1c = wb[64]; b2c = wb[128]; b3c = wb[192];

  for (int kt = 0; kt < KTILES; ++kt){
    if (kt + 1 < KTILES){
      LOAD_A(kt + 1, afn);
      b0n = wb[((kt+1)*4+0)*64];
      b1n = wb[((kt+1)*4+1)*64];
      b2n = wb[((kt+1)*4+2)*64];
      b3n = wb[((kt+1)*4+3)*64];
    }
    acc0 = __builtin_amdgcn_mfma_f32_16x16x32_bf16(afc, b0c, acc0, 0,0,0);
    acc1 = __builtin_amdgcn_mfma_f32_16x16x32_bf16(afc, b1c, acc1, 0,0,0);
    acc2 = __builtin_amdgcn_mfma_f32_16x16x32_bf16(afc, b2c, acc2, 0,0,0);
    acc3 = __builtin_amdgcn_mfma_f32_16x16x32_bf16(afc, b3c, acc3, 0,0,0);
    afc = afn; b0c = b0n; b1c = b1n; b2c = b2n; b3c = b3n;
  }
  #undef LOAD_A

  // C/D: col = lane&15, row = (lane>>4)*4 + reg
  int orow = row0 + g*4;
  float d0 = dinv[orow], d1 = dinv[orow+1], d2 = dinv[orow+2], d3 = dinv[orow+3];
  unsigned short* op = out + (size_t)orow*64 + r;
  op[0*64 +  0] = (unsigned short)f2bf(acc0[0]*d0);
  op[0*64 + 16] = (unsigned short)f2bf(acc1[0]*d0);
  op[0*64 + 32] = (unsigned short)f2bf(acc2[0]*d0);
  op[0*64 + 48] = (unsigned short)f2bf(acc3[0]*d0);
  op[1*64 +  0] = (unsigned short)f2bf(acc0[1]*d1);
  op[1*64 + 16] = (unsigned short)f2bf(acc1[1]*d1);
  op[1*64 + 32] = (unsigned short)f2bf(acc2[1]*d1);
  op[1*64 + 48] = (unsigned short)f2bf(acc3[1]*d1);
  op[2*64 +  0] = (unsigned short)f2bf(acc0[2]*d2);
  op[2*64 + 16] = (unsigned short)f2bf(acc1[2]*d2);
  op[2*64 + 32] = (unsigned short)f2bf(acc2[2]*d2);
  op[2*64 + 48] = (unsigned short)f2bf(acc3[2]*d2);
  op[3*64 +  0] = (unsigned short)f2bf(acc0[3]*d3);
  op[3*64 + 16] = (unsigned short)f2bf(acc1[3]*d3);
  op[3*64 + 32] = (unsigned short)f2bf(acc2[3]*d3);
  op[3*64 + 48] = (unsigned short)f2bf(acc3[3]*d3);
}

// Pure gather-accumulate: acc[i] = h'[i] + sum_{s in N(i)} h'[s]  (h' pre-scaled by dinv[src])
// z = relu(dinv[i]*acc + b). FUSE: accumulate mean partials; else store z as bf16.
template<bool FUSE>
__global__ __launch_bounds__(256) void k_agg(const unsigned short* __restrict__ hin, const int* __restrict__ off,
                                             const int* __restrict__ ebuf, const float* __restrict__ dinv,
                                             const float* __restrict__ bias, void* __restrict__ outp, int N){
  int lane = threadIdx.x & 63, wid = threadIdx.x >> 6;
  float b = bias[lane];
  float fsum = 0.f;
  int stride = gridDim.x*4;
  for (int i = blockIdx.x*4 + wid; i < N; i += stride){
    float acc = bf2f(hin[(size_t)i*64 + lane]);   // self-loop term h'[i]
    int j  = off[i];
    int j1 = off[i+1];
    for (; j + 4 <= j1; j += 4){
      int s0 = ebuf[j], s1 = ebuf[j+1], s2 = ebuf[j+2], s3 = ebuf[j+3];
      acc += bf2f(hin[(size_t)s0*64 + lane]);
      acc += bf2f(hin[(size_t)s1*64 + lane]);
      acc += bf2f(hin[(size_t)s2*64 + lane]);
      acc += bf2f(hin[(size_t)s3*64 + lane]);
    }
    for (; j < j1; ++j){
      int s = ebuf[j];
      acc += bf2f(hin[(size_t)s*64 + lane]);
    }
    float z = fmaxf(dinv[i]*acc + b, 0.f);
    if (FUSE) fsum += z;
    else ((unsigned short*)outp)[(size_t)i*64 + lane] = (unsigned short)f2bf(z);
  }
  if (FUSE){
    __shared__ float sm[4][64];
    sm[wid][lane] = fsum;
    __syncthreads();
    if (wid == 0)
      ((float*)outp)[(size_t)blockIdx.x*64 + lane] = sm[0][lane] + sm[1][lane] + sm[2][lane] + sm[3][lane];
  }
}

__global__ __launch_bounds__(256) void k_final(const float* __restrict__ part, float* __restrict__ out,
                                               int NB, float invN){
  int f = blockIdx.x;
  float s = 0.f;
  for (int b = threadIdx.x; b < NB; b += 256) s += part[(size_t)b*64 + f];
  __shared__ float sm[256];
  sm[threadIdx.x] = s; __syncthreads();
  for (int d = 128; d > 0; d >>= 1){
    if (threadIdx.x < d) sm[threadIdx.x] += sm[threadIdx.x + d];
    __syncthreads();
  }
  if (threadIdx.x == 0) out[f] = sm[0]*invN;
}

extern "C" void kernel_launch(void* const* d_in, const int* in_sizes, int n_in,
                              void* d_out, int out_size, void* d_ws, size_t ws_size,
                              hipStream_t stream){
  const float* x  = (const float*)d_in[0];
  const int*   ei = (const int*)d_in[1];
  const float* W1 = (const float*)d_in[2];
  const float* b1 = (const float*)d_in[3];
  const float* W2 = (const float*)d_in[4];
  const float* b2 = (const float*)d_in[5];
  float* out = (float*)d_out;

  const int IN = 2048;
  int N = in_sizes[0] / IN;      // 50000
  int E = in_sizes[1] / 2;       // 1.6M

  char* w = (char*)d_ws;
  auto alloc = [&](size_t bytes){ char* p = w; w += (bytes + 255) & ~255ULL; return (void*)p; };
  int*   cnt    = (int*)  alloc((size_t)N*4);
  int*   off    = (int*)  alloc((size_t)(N+1)*4);
  int*   cursor = (int*)  alloc((size_t)N*4);
  float* dinv   = (float*)alloc((size_t)N*4);
  int*   ebuf   = (int*)  alloc((size_t)E*4);
  short* Wb1    = (short*)alloc((size_t)64*2048*2);  // KTILES=64 fragments
  short* Wb2    = (short*)alloc((size_t)2*2048*2);   // KTILES=2 fragments
  unsigned short* h1 = (unsigned short*)alloc((size_t)N*64*2); // bf16 h' (reused for h2')
  unsigned short* z1 = (unsigned short*)alloc((size_t)N*64*2); // bf16 z1
  const int NB2 = 2048;
  float* part   = (float*)alloc((size_t)NB2*64*4);

  int eb = (E + 255)/256;
  k_zero_i32<<<(N+255)/256, 256, 0, stream>>>(cnt, N);
  k_hist   <<<eb, 256, 0, stream>>>(ei, cnt, E);
  k_scan   <<<1, 1024, 0, stream>>>(cnt, off, cursor, dinv, N);
  k_scatter<<<eb, 256, 0, stream>>>(ei, cursor, ebuf, E);
  k_wconv  <<<(64*2048 + 255)/256, 256, 0, stream>>>(W1, Wb1, 64*2048);
  k_wconv  <<<(2*2048  + 255)/256, 256, 0, stream>>>(W2, Wb2, 2*2048);

  int mtiles  = (N + 15)/16;         // 3125
  int gblocks = (mtiles + 3)/4;      // 782
  k_gemm<64,false><<<gblocks, 256, 0, stream>>>(x, nullptr, Wb1, dinv, h1, N, 2048);
  k_agg<false><<<NB2, 256, 0, stream>>>(h1, off, ebuf, dinv, b1, (void*)z1, N);
  k_gemm<2,true> <<<gblocks, 256, 0, stream>>>(nullptr, z1, Wb2, dinv, h1, N, 64);
  k_agg<true> <<<NB2, 256, 0, stream>>>(h1, off, ebuf, dinv, b2, (void*)part, N);
  k_final  <<<64, 256, 0, stream>>>(part, out, NB2, 1.0f/(float)N);
}

// Round 3
// 581.044 us; speedup vs baseline: 1.0383x; 1.0245x over previous
//
#include <hip/hip_runtime.h>
#include <hip/hip_bf16.h>

typedef __attribute__((ext_vector_type(8))) short short8_t;
typedef __attribute__((ext_vector_type(4))) float f32x4;

__device__ __forceinline__ short f2bf(float x){
  union { float f; unsigned u; } v; v.f = x;
  unsigned r = v.u + 0x7fffu + ((v.u >> 16) & 1u);
  return (short)(r >> 16);
}
__device__ __forceinline__ unsigned pack2(float lo, float hi){
  return (unsigned)(unsigned short)f2bf(lo) | ((unsigned)(unsigned short)f2bf(hi) << 16);
}
__device__ __forceinline__ float bf2f(unsigned short u){
  union { unsigned u; float f; } v; v.u = ((unsigned)u) << 16; return v.f;
}

__global__ __launch_bounds__(256) void k_zero_i32(int* __restrict__ p, int n){
  int i = blockIdx.x*256 + threadIdx.x;
  if (i < n) p[i] = 0;
}

__global__ __launch_bounds__(256) void k_hist(const int* __restrict__ ei, int* __restrict__ cnt, int E){
  int i = blockIdx.x*256 + threadIdx.x;
  if (i < E) atomicAdd(&cnt[ei[E + i]], 1);
}

__global__ __launch_bounds__(1024) void k_scan(const int* __restrict__ cnt, int* __restrict__ off,
                                               int* __restrict__ cursor, float* __restrict__ dinv, int N){
  __shared__ int part[1024];
  int t = threadIdx.x;
  int chunk = (N + 1023) >> 10;
  int lo = t*chunk; if (lo > N) lo = N;
  int hi = lo + chunk; if (hi > N) hi = N;
  int s = 0;
  for (int i = lo; i < hi; ++i) s += cnt[i];
  part[t] = s; __syncthreads();
  for (int d = 1; d < 1024; d <<= 1){
    int v = (t >= d) ? part[t-d] : 0;
    __syncthreads();
    part[t] += v;
    __syncthreads();
  }
  int run = (t == 0) ? 0 : part[t-1];
  for (int i = lo; i < hi; ++i){
    off[i] = run; cursor[i] = run;
    dinv[i] = rsqrtf((float)(cnt[i] + 1));
    run += cnt[i];
  }
  if (t == 1023) off[N] = part[1023];
}

__global__ __launch_bounds__(256) void k_scatter(const int* __restrict__ ei, int* __restrict__ cursor,
                                                 int* __restrict__ ebuf, int E){
  int i = blockIdx.x*256 + threadIdx.x;
  if (i < E){
    int s = ei[i], d = ei[E + i];
    int p = atomicAdd(&cursor[d], 1);
    ebuf[p] = s;
  }
}

// W [K x 64] fp32 -> bf16 fragment layout.
// tid = ((kt*4 + nt)*64 + lane)*8 + e ; element = W[(kt*32 + (lane>>4)*8 + e)*64 + nt*16 + (lane&15)]
__global__ __launch_bounds__(256) void k_wconv(const float* __restrict__ W, short* __restrict__ Wb, int total){
  int tid = blockIdx.x*256 + threadIdx.x;
  if (tid >= total) return;
  int e  = tid & 7;
  int l  = (tid >> 3) & 63;
  int nt = (tid >> 9) & 3;
  int kt = tid >> 11;
  int k  = kt*32 + (l >> 4)*8 + e;
  int col = nt*16 + (l & 15);
  Wb[tid] = f2bf(W[(size_t)k*64 + col]);
}

// GEMM1: C = A[M x 2048] * W[2048 x 64]; out bf16 h' = dinv[row]*C[row].
// Block = 4 waves x 16 rows. Per wave: stage own 16 rows x 256 cols into LDS
// (coalesced 1KB/instr loads, bf16, XOR-swizzled 16B blocks), then MFMA from LDS.
// No cross-wave LDS sharing -> no __syncthreads.
__global__ __launch_bounds__(256) void k_gemm1(const float* __restrict__ A, const short* __restrict__ Wb,
                                               const float* __restrict__ dinv, unsigned short* __restrict__ out,
                                               int M){
  __shared__ unsigned short lds[64*256];   // 32 KB: 64 rows x 256 bf16 (pitch 512 B)
  int wid = threadIdx.x >> 6, lane = threadIdx.x & 63;
  int row0 = blockIdx.x*64 + wid*16;
  if (row0 >= M) return;
  int rfrag = lane & 15, g = lane >> 4;
  char* ldsb = (char*)lds;
  const short8_t* wb = (const short8_t*)Wb + lane;
  f32x4 acc0 = {0.f,0.f,0.f,0.f}, acc1 = acc0, acc2 = acc0, acc3 = acc0;

  int wbase = wid*16*512;                      // wave's LDS byte base
  int wsel  = (lane >> 1);                     // 16B block owned by this lane on writes
  int whalf = (lane & 1) << 3;

  for (int ko = 0; ko < 8; ++ko){
    // ---- stage: 16 rows x 256 cols, 1 KB contiguous per wave-instr ----
    #pragma unroll
    for (int r = 0; r < 16; ++r){
      const float4 a = *(const float4*)(A + (size_t)(row0 + r)*2048 + ko*256 + lane*4);
      uint2 p; p.x = pack2(a.x, a.y); p.y = pack2(a.z, a.w);
      *(uint2*)(ldsb + wbase + r*512 + ((wsel ^ (r & 7)) << 4) + whalf) = p;
    }
    asm volatile("s_waitcnt lgkmcnt(0)" ::: "memory");
    // ---- consume: 8 k-subtiles of 32 ----
    #pragma unroll
    for (int kt = 0; kt < 8; ++kt){
      short8_t af = *(const short8_t*)(ldsb + wbase + rfrag*512 + ((((kt<<2) + g) ^ (rfrag & 7)) << 4));
      int ktg = ko*8 + kt;
      short8_t b0 = wb[(ktg*4+0)*64];
      short8_t b1 = wb[(ktg*4+1)*64];
      short8_t b2 = wb[(ktg*4+2)*64];
      short8_t b3 = wb[(ktg*4+3)*64];
      acc0 = __builtin_amdgcn_mfma_f32_16x16x32_bf16(af, b0, acc0, 0,0,0);
      acc1 = __builtin_amdgcn_mfma_f32_16x16x32_bf16(af, b1, acc1, 0,0,0);
      acc2 = __builtin_amdgcn_mfma_f32_16x16x32_bf16(af, b2, acc2, 0,0,0);
      acc3 = __builtin_amdgcn_mfma_f32_16x16x32_bf16(af, b3, acc3, 0,0,0);
    }
  }

  // C/D: col = lane&15, row = (lane>>4)*4 + reg
  int orow = row0 + g*4;
  float d0 = dinv[orow], d1 = dinv[orow+1], d2 = dinv[orow+2], d3 = dinv[orow+3];
  unsigned short* op = out + (size_t)orow*64 + rfrag;
  op[0*64 +  0] = (unsigned short)f2bf(acc0[0]*d0);
  op[0*64 + 16] = (unsigned short)f2bf(acc1[0]*d0);
  op[0*64 + 32] = (unsigned short)f2bf(acc2[0]*d0);
  op[0*64 + 48] = (unsigned short)f2bf(acc3[0]*d0);
  op[1*64 +  0] = (unsigned short)f2bf(acc0[1]*d1);
  op[1*64 + 16] = (unsigned short)f2bf(acc1[1]*d1);
  op[1*64 + 32] = (unsigned short)f2bf(acc2[1]*d1);
  op[1*64 + 48] = (unsigned short)f2bf(acc3[1]*d1);
  op[2*64 +  0] = (unsigned short)f2bf(acc0[2]*d2);
  op[2*64 + 16] = (unsigned short)f2bf(acc1[2]*d2);
  op[2*64 + 32] = (unsigned short)f2bf(acc2[2]*d2);
  op[2*64 + 48] = (unsigned short)f2bf(acc3[2]*d2);
  op[3*64 +  0] = (unsigned short)f2bf(acc0[3]*d3);
  op[3*64 + 16] = (unsigned short)f2bf(acc1[3]*d3);
  op[3*64 + 32] = (unsigned short)f2bf(acc2[3]*d3);
  op[3*64 + 48] = (unsigned short)f2bf(acc3[3]*d3);
}

// GEMM2 (K=64): A is bf16 (z1), read directly; same fragment/output scheme.
template<int KTILES>
__global__ __launch_bounds__(256) void k_gemm_sm(const unsigned short* __restrict__ Ah,
                                                 const short* __restrict__ Wb, const float* __restrict__ dinv,
                                                 unsigned short* __restrict__ out, int M, int lda){
  int wid = threadIdx.x >> 6, lane = threadIdx.x & 63;
  int row0 = (blockIdx.x*4 + wid)*16;
  if (row0 >= M) return;
  int r = lane & 15, g = lane >> 4;
  const short8_t* wb = (const short8_t*)Wb + lane;
  f32x4 acc0 = {0.f,0.f,0.f,0.f}, acc1 = acc0, acc2 = acc0, acc3 = acc0;
  #pragma unroll
  for (int kt = 0; kt < KTILES; ++kt){
    short8_t af = *(const short8_t*)(Ah + (size_t)(row0 + r)*lda + kt*32 + g*8);
    short8_t b0 = wb[(kt*4+0)*64];
    short8_t b1 = wb[(kt*4+1)*64];
    short8_t b2 = wb[(kt*4+2)*64];
    short8_t b3 = wb[(kt*4+3)*64];
    acc0 = __builtin_amdgcn_mfma_f32_16x16x32_bf16(af, b0, acc0, 0,0,0);
    acc1 = __builtin_amdgcn_mfma_f32_16x16x32_bf16(af, b1, acc1, 0,0,0);
    acc2 = __builtin_amdgcn_mfma_f32_16x16x32_bf16(af, b2, acc2, 0,0,0);
    acc3 = __builtin_amdgcn_mfma_f32_16x16x32_bf16(af, b3, acc3, 0,0,0);
  }
  int orow = row0 + g*4;
  float d0 = dinv[orow], d1 = dinv[orow+1], d2 = dinv[orow+2], d3 = dinv[orow+3];
  unsigned short* op = out + (size_t)orow*64 + r;
  op[0*64 +  0] = (unsigned short)f2bf(acc0[0]*d0);
  op[0*64 + 16] = (unsigned short)f2bf(acc1[0]*d0);
  op[0*64 + 32] = (unsigned short)f2bf(acc2[0]*d0);
  op[0*64 + 48] = (unsigned short)f2bf(acc3[0]*d0);
  op[1*64 +  0] = (unsigned short)f2bf(acc0[1]*d1);
  op[1*64 + 16] = (unsigned short)f2bf(acc1[1]*d1);
  op[1*64 + 32] = (unsigned short)f2bf(acc2[1]*d1);
  op[1*64 + 48] = (unsigned short)f2bf(acc3[1]*d1);
  op[2*64 +  0] = (unsigned short)f2bf(acc0[2]*d2);
  op[2*64 + 16] = (unsigned short)f2bf(acc1[2]*d2);
  op[2*64 + 32] = (unsigned short)f2bf(acc2[2]*d2);
  op[2*64 + 48] = (unsigned short)f2bf(acc3[2]*d2);
  op[3*64 +  0] = (unsigned short)f2bf(acc0[3]*d3);
  op[3*64 + 16] = (unsigned short)f2bf(acc1[3]*d3);
  op[3*64 + 32] = (unsigned short)f2bf(acc2[3]*d3);
  op[3*64 + 48] = (unsigned short)f2bf(acc3[3]*d3);
}

// Gather-accumulate: acc[i] = h'[i] + sum_{s in N(i)} h'[s]; z = relu(dinv[i]*acc + b).
template<bool FUSE>
__global__ __launch_bounds__(256) void k_agg(const unsigned short* __restrict__ hin, const int* __restrict__ off,
                                             const int* __restrict__ ebuf, const float* __restrict__ dinv,
                                             const float* __restrict__ bias, void* __restrict__ outp, int N){
  int lane = threadIdx.x & 63, wid = threadIdx.x >> 6;
  float b = bias[lane];
  float fsum = 0.f;
  int stride = gridDim.x*4;
  for (int i = blockIdx.x*4 + wid; i < N; i += stride){
    float acc = bf2f(hin[(size_t)i*64 + lane]);
    int j  = off[i];
    int j1 = off[i+1];
    for (; j + 4 <= j1; j += 4){
      int s0 = ebuf[j], s1 = ebuf[j+1], s2 = ebuf[j+2], s3 = ebuf[j+3];
      acc += bf2f(hin[(size_t)s0*64 + lane]);
      acc += bf2f(hin[(size_t)s1*64 + lane]);
      acc += bf2f(hin[(size_t)s2*64 + lane]);
      acc += bf2f(hin[(size_t)s3*64 + lane]);
    }
    for (; j < j1; ++j){
      int s = ebuf[j];
      acc += bf2f(hin[(size_t)s*64 + lane]);
    }
    float z = fmaxf(dinv[i]*acc + b, 0.f);
    if (FUSE) fsum += z;
    else ((unsigned short*)outp)[(size_t)i*64 + lane] = (unsigned short)f2bf(z);
  }
  if (FUSE){
    __shared__ float sm[4][64];
    sm[wid][lane] = fsum;
    __syncthreads();
    if (wid == 0)
      ((float*)outp)[(size_t)blockIdx.x*64 + lane] = sm[0][lane] + sm[1][lane] + sm[2][lane] + sm[3][lane];
  }
}

__global__ __launch_bounds__(256) void k_final(const float* __restrict__ part, float* __restrict__ out,
                                               int NB, float invN){
  int f = blockIdx.x;
  float s = 0.f;
  for (int b = threadIdx.x; b < NB; b += 256) s += part[(size_t)b*64 + f];
  __shared__ float sm[256];
  sm[threadIdx.x] = s; __syncthreads();
  for (int d = 128; d > 0; d >>= 1){
    if (threadIdx.x < d) sm[threadIdx.x] += sm[threadIdx.x + d];
    __syncthreads();
  }
  if (threadIdx.x == 0) out[f] = sm[0]*invN;
}

extern "C" void kernel_launch(void* const* d_in, const int* in_sizes, int n_in,
                              void* d_out, int out_size, void* d_ws, size_t ws_size,
                              hipStream_t stream){
  const float* x  = (const float*)d_in[0];
  const int*   ei = (const int*)d_in[1];
  const float* W1 = (const float*)d_in[2];
  const float* b1 = (const float*)d_in[3];
  const float* W2 = (const float*)d_in[4];
  const float* b2 = (const float*)d_in[5];
  float* out = (float*)d_out;

  const int IN = 2048;
  int N = in_sizes[0] / IN;      // 50000
  int E = in_sizes[1] / 2;       // 1.6M

  char* w = (char*)d_ws;
  auto alloc = [&](size_t bytes){ char* p = w; w += (bytes + 255) & ~255ULL; return (void*)p; };
  int*   cnt    = (int*)  alloc((size_t)N*4);
  int*   off    = (int*)  alloc((size_t)(N+1)*4);
  int*   cursor = (int*)  alloc((size_t)N*4);
  float* dinv   = (float*)alloc((size_t)N*4);
  int*   ebuf   = (int*)  alloc((size_t)E*4);
  short* Wb1    = (short*)alloc((size_t)64*2048*2);
  short* Wb2    = (short*)alloc((size_t)2*2048*2);
  unsigned short* h1 = (unsigned short*)alloc((size_t)N*64*2);
  unsigned short* z1 = (unsigned short*)alloc((size_t)N*64*2);
  const int NB2 = 2048;
  float* part   = (float*)alloc((size_t)NB2*64*4);

  int eb = (E + 255)/256;
  k_zero_i32<<<(N+255)/256, 256, 0, stream>>>(cnt, N);
  k_hist   <<<eb, 256, 0, stream>>>(ei, cnt, E);
  k_scan   <<<1, 1024, 0, stream>>>(cnt, off, cursor, dinv, N);
  k_scatter<<<eb, 256, 0, stream>>>(ei, cursor, ebuf, E);
  k_wconv  <<<(64*2048 + 255)/256, 256, 0, stream>>>(W1, Wb1, 64*2048);
  k_wconv  <<<(2*2048  + 255)/256, 256, 0, stream>>>(W2, Wb2, 2*2048);

  int b1blocks = (N + 63)/64;        // 782 (64 rows per block)
  int smblocks = ((N + 15)/16 + 3)/4;
  k_gemm1<<<b1blocks, 256, 0, stream>>>(x, Wb1, dinv, h1, N);
  k_agg<false><<<NB2, 256, 0, stream>>>(h1, off, ebuf, dinv, b1, (void*)z1, N);
  k_gemm_sm<2><<<smblocks, 256, 0, stream>>>(z1, Wb2, dinv, h1, N, 64);
  k_agg<true> <<<NB2, 256, 0, stream>>>(h1, off, ebuf, dinv, b2, (void*)part, N);
  k_final  <<<64, 256, 0, stream>>>(part, out, NB2, 1.0f/(float)N);
}